// Round 17
// baseline (78.374 us; speedup 1.0000x reference)
//
#include <hip/hip_runtime.h>

#define NM    20           // nmax
#define NP1   21
#define PTSC  4            // points per chunk
#define BLK   64           // one wave
#define ROWF  882          // floats per point
#define CHF   (PTSC * ROWF)   // 3528 floats per chunk
#define CHF4  (CHF / 4)       // 882 f32x4 per chunk
#define FULLS (CHF4 / BLK)    // 13 full sweeps
#define TAILS (CHF4 - FULLS * BLK) // 50
#define CPB   8            // chunks per block

typedef float f32x4 __attribute__((ext_vector_type(4)));
typedef float f32x2 __attribute__((ext_vector_type(2)));

struct Tbl {
    float dprod[NP1];      // INV_SQRT_4PI * prod_{k<=m} (-sqrt((2k+1)/(2k)))  (CS phase)
    float e[NP1];          // sqrt(2m+3)
    float a[NP1][NP1];
    float b[NP1][NP1];
};

constexpr double csqrt_d(double x) {
    double r = x * 0.5 + 0.5;
    for (int i = 0; i < 48; ++i) r = 0.5 * (r + x / r);
    return r;
}

constexpr Tbl make_tbl() {
    Tbl t{};
    const double inv4pi = 0.28209479177387814;
    double dp = inv4pi;
    t.dprod[0] = (float)dp;
    for (int m = 1; m <= NM; ++m) {
        dp *= -csqrt_d((2.0 * m + 1.0) / (2.0 * m));
        t.dprod[m] = (float)dp;
    }
    for (int m = 0; m <= NM; ++m) t.e[m] = (float)csqrt_d(2.0 * m + 3.0);
    for (int m = 0; m <= NM; ++m)
        for (int n = m + 2; n <= NM; ++n) {
            double nn = (double)n * n, mm = (double)m * m;
            t.a[m][n] = (float)csqrt_d((4.0 * nn - 1.0) / (nn - mm));
            t.b[m][n] = (float)csqrt_d((2.0 * n + 1.0) * (n - 1.0 - m) * (n - 1.0 + m) /
                                       ((2.0 * n - 3.0) * (nn - mm)));
        }
    return t;
}

__constant__ Tbl TBL = make_tbl();

// Taylor sin/cos for t in [0,1.5): max err ~1e-6 over [0,1).
__device__ __forceinline__ void sincos_small(float t, float& sn, float& cs) {
    const float t2 = t * t;
    sn = t * (1.0f + t2 * (-1.0f/6.0f + t2 * (1.0f/120.0f + t2 * (-1.0f/5040.0f))));
    cs = 1.0f + t2 * (-0.5f + t2 * (1.0f/24.0f + t2 * (-1.0f/720.0f + t2 * (1.0f/40320.0f))));
}

// In-flight-store design: one wave per block, 8 chunks of 4 points. Per chunk:
// compute (2 passes of 2 points, 32 lanes/pt) -> LDS image -> stage ALL 882
// f32x4 into 14 distinct reg quads -> 14-instr nt-store burst. Next chunk's
// compute (~1600 cyc) overlaps the drain of those stores; the WAR wait on the
// staging regs lands after compute, when vmcnt has already fallen. No barriers.
// Model (R14/R15 evidence): composites plateau at ~4.2-4.6 TB/s because only
// ~7KB of stores/CU are in flight; this keeps ~3x more in flight continuously.
__global__ __launch_bounds__(BLK) void sph_kernel(const float* __restrict__ theta,
                                                  const float* __restrict__ phi,
                                                  float* __restrict__ out,
                                                  int npts, int nchunks) {
    __shared__ __align__(16) float sh[PTSC][ROWF];
    const int lane = threadIdx.x;
    const int pt2  = lane >> 5;        // 0..1: point within compute pass
    const int col  = lane & 31;        // m-column (active if <=20)

    f32x4 stage[FULLS + 1];

    #pragma unroll 1
    for (int i = 0; i < CPB; ++i) {
        const int c = blockIdx.x * CPB + i;
        if (c >= nchunks) break;
        const int gpt0 = c * PTSC;

        // ---- compute 4 points (2 passes of 2) into LDS image ----
        #pragma unroll
        for (int half = 0; half < 2; ++half) {
            const int gpt = gpt0 + half * 2 + pt2;
            if (gpt < npts && col <= NM) {
                const float th = theta[gpt];
                const float ph = phi[gpt];
                float st, ct, s, x;
                sincos_small(th, st, ct);      // e^{i*theta}
                sincos_small(ph, s, x);        // s = sin(phi), x = cos(phi)
                float* row = sh[half * 2 + pt2];
                const int m = col;

                // W = (s*e^{i*th})^m via 5-step binary exponentiation
                float wc = 1.0f, ws = 0.0f;
                float bc = s * ct, bs = s * st;
                int mb = m;
                #pragma unroll
                for (int k = 0; k < 5; ++k) {
                    const float nwc = wc * bc - ws * bs;
                    const float nws = wc * bs + ws * bc;
                    wc = (mb & 1) ? nwc : wc;
                    ws = (mb & 1) ? nws : ws;
                    mb >>= 1;
                    const float t = bc * bc - bs * bs;
                    bs = 2.0f * bc * bs;
                    bc = t;
                }
                const float wcn = (m & 1) ? -wc : wc;   // -m signs pre-applied
                const float wsn = (m & 1) ?  ws : -ws;

                float qb = 0.0f, qa = TBL.dprod[m];     // Q = P / s^m
                int nn = m * (m + 1);
                for (int n = m; n <= NM; ++n) {
                    *reinterpret_cast<float2*>(row + 2 * (nn + m)) = make_float2(qa * wc, qa * ws);
                    if (m > 0)
                        *reinterpret_cast<float2*>(row + 2 * (nn - m)) = make_float2(qa * wcn, qa * wsn);
                    if (n < NM) {
                        const float qn = (n == m) ? TBL.e[m] * x * qa
                                                  : TBL.a[m][n + 1] * x * qa - TBL.b[m][n + 1] * qb;
                        qb = qa; qa = qn;
                    }
                    nn += 2 * (n + 1);
                }
            }
        }
        // no barrier: single-wave block, same-wave DS ordering via lgkmcnt

        // ---- stage to 14 distinct reg quads, then burst all stores ----
        if (gpt0 + PTSC <= npts) {
            const f32x4* __restrict__ src = reinterpret_cast<const f32x4*>(&sh[0][0]);
            f32x4* __restrict__ dst = reinterpret_cast<f32x4*>(out) + (long long)c * CHF4;
            #pragma unroll
            for (int k = 0; k < FULLS; ++k) stage[k] = src[lane + k * BLK];
            const bool hastail = lane < TAILS;
            if (hastail) stage[FULLS] = src[FULLS * BLK + lane];
            __builtin_amdgcn_sched_barrier(0);   // all LDS reads before any store
            #pragma unroll
            for (int k = 0; k < FULLS; ++k)
                __builtin_nontemporal_store(stage[k], dst + lane + k * BLK);
            if (hastail) __builtin_nontemporal_store(stage[FULLS], dst + FULLS * BLK + lane);
        } else {                                 // partial last chunk (safety)
            const int vpts = npts - gpt0;
            if (vpts > 0) {
                const f32x2* __restrict__ src = reinterpret_cast<const f32x2*>(&sh[0][0]);
                f32x2* __restrict__ dst = reinterpret_cast<f32x2*>(out) + (long long)gpt0 * (ROWF / 2);
                for (int j = lane; j < vpts * (ROWF / 2); j += BLK)
                    __builtin_nontemporal_store(src[j], dst + j);
            }
        }
    }
}

extern "C" void kernel_launch(void* const* d_in, const int* in_sizes, int n_in,
                              void* d_out, int out_size, void* d_ws, size_t ws_size,
                              hipStream_t stream) {
    const float* theta = (const float*)d_in[0];
    const float* phi   = (const float*)d_in[1];
    float* out = (float*)d_out;
    const int npts = in_sizes[0];
    const int nchunks = (npts + PTSC - 1) / PTSC;     // 16384
    const int grid = (nchunks + CPB - 1) / CPB;       // 2048
    sph_kernel<<<grid, BLK, 0, stream>>>(theta, phi, out, npts, nchunks);
}